// Round 2
// baseline (248.299 us; speedup 1.0000x reference)
//
#include <hip/hip_runtime.h>
#include <math.h>

// SSIM fused kernel for MI355X (gfx950), v2.
// A,B: [16,3,512,512] f32 -> scalar f32 mean(ssim_map).
// Separable 11-tap Gaussian, zero-padded SAME conv.
// v2: TY 32->16 (4 blocks/CU, 16 waves), products-once h-pass with float4
// window loads, float2 LDS reads in v-pass, rcp+NR division.

#define TX 64
#define TY 16
#define SR 26            // TY + 10 rows of h-conv results
#define LS 68            // LDS row stride in floats (bank spread + 16B align)
#define IMG 512
#define C1F 1.0e-4f
#define C2F 9.0e-4f

__global__ void ssim_zero(double* acc) { *acc = 0.0; }

__global__ void ssim_finalize(const double* acc, float* out) {
    *out = (float)(*acc / 12582912.0);   // 16*3*512*512
}

__global__ __launch_bounds__(256, 4)
void ssim_main(const float* __restrict__ A, const float* __restrict__ B,
               double* __restrict__ acc)
{
    // 5 h-conv planes: hA, hB, hAA, hBB, hAB. 5*26*68*4 = 35360 B -> 4 blk/CU
    __shared__ float h[5][SR * LS];

    const int t  = threadIdx.x;
    const int x0 = blockIdx.x * TX;
    const int y0 = blockIdx.y * TY;
    const size_t pbase = (size_t)blockIdx.z * (size_t)(IMG * IMG);
    const float* __restrict__ pa = A + pbase;
    const float* __restrict__ pb = B + pbase;

    // Gaussian weights (identical fp32 formula to reference; 2*sigma^2 = 4.5)
    float g[11];
    {
        float gs = 0.f;
        #pragma unroll
        for (int i = 0; i < 11; ++i) {
            const float d = (float)(i - 5);
            g[i] = expf(-d * d / 4.5f);
            gs += g[i];
        }
        #pragma unroll
        for (int i = 0; i < 11; ++i) g[i] /= gs;
    }

    // ---------------- horizontal pass ----------------
    // 208 threads: thread = (r = t>>3 in 0..25, s = t&7). Outputs cols
    // xb..xb+7 (xb = x0+8s) of h-row r. Inputs cols xb-5..xb+12; we stage a
    // 24-float window [xb-8, xb+15] (16B-aligned) so interior is 6 float4s.
    if (t < 208) {
        const int r  = t >> 3;
        const int s  = t & 7;
        const int gy = y0 - 5 + r;
        const int xb = x0 + 8 * s;
        const bool rowok = ((unsigned)gy < (unsigned)IMG);
        const float* __restrict__ ra = pa + (ptrdiff_t)gy * IMG;
        const float* __restrict__ rb = pb + (ptrdiff_t)gy * IMG;

        float wa[24], wb[24];
        if (rowok && xb >= 8 && xb <= IMG - 16) {
            const float4* va = (const float4*)(ra + xb - 8);
            const float4* vb = (const float4*)(rb + xb - 8);
            #pragma unroll
            for (int q = 0; q < 6; ++q) {
                const float4 qa = va[q], qb = vb[q];
                wa[4*q+0] = qa.x; wa[4*q+1] = qa.y; wa[4*q+2] = qa.z; wa[4*q+3] = qa.w;
                wb[4*q+0] = qb.x; wb[4*q+1] = qb.y; wb[4*q+2] = qb.z; wb[4*q+3] = qb.w;
            }
        } else {
            #pragma unroll
            for (int i = 0; i < 24; ++i) {
                const int gx = xb - 8 + i;
                const bool ok = rowok && ((unsigned)gx < (unsigned)IMG);
                wa[i] = ok ? ra[gx] : 0.f;
                wb[i] = ok ? rb[gx] : 0.f;
            }
        }

        // products-once, scatter into 8 outputs x 5 signals
        float sa[8], sb[8], saa[8], sbb[8], sab[8];
        #pragma unroll
        for (int p = 0; p < 8; ++p) { sa[p]=0.f; sb[p]=0.f; saa[p]=0.f; sbb[p]=0.f; sab[p]=0.f; }
        #pragma unroll
        for (int m = 0; m < 18; ++m) {          // input col = xb-5+m = window[m+3]
            const float a = wa[m + 3];
            const float b = wb[m + 3];
            const float aa = a * a, bb = b * b, ab = a * b;
            #pragma unroll
            for (int p = 0; p < 8; ++p) {
                const int k = m - p;            // tap index
                if (k >= 0 && k <= 10) {
                    const float w = g[k];
                    sa[p]  += w * a;  sb[p]  += w * b;
                    saa[p] += w * aa; sbb[p] += w * bb; sab[p] += w * ab;
                }
            }
        }
        const int o = r * LS + 8 * s;           // 16B-aligned (LS, 8s mult of 4)
        *(float4*)&h[0][o]   = make_float4(sa[0],  sa[1],  sa[2],  sa[3]);
        *(float4*)&h[0][o+4] = make_float4(sa[4],  sa[5],  sa[6],  sa[7]);
        *(float4*)&h[1][o]   = make_float4(sb[0],  sb[1],  sb[2],  sb[3]);
        *(float4*)&h[1][o+4] = make_float4(sb[4],  sb[5],  sb[6],  sb[7]);
        *(float4*)&h[2][o]   = make_float4(saa[0], saa[1], saa[2], saa[3]);
        *(float4*)&h[2][o+4] = make_float4(saa[4], saa[5], saa[6], saa[7]);
        *(float4*)&h[3][o]   = make_float4(sbb[0], sbb[1], sbb[2], sbb[3]);
        *(float4*)&h[3][o+4] = make_float4(sbb[4], sbb[5], sbb[6], sbb[7]);
        *(float4*)&h[4][o]   = make_float4(sab[0], sab[1], sab[2], sab[3]);
        *(float4*)&h[4][o+4] = make_float4(sab[4], sab[5], sab[6], sab[7]);
    }
    __syncthreads();

    // ---------------- vertical pass + SSIM ----------------
    // 256 threads: thread = (xp = t&31 -> cols 2*xp,2*xp+1; grp = t>>5 ->
    // output rows yb=2*grp, yb+1). Streams 12 h-rows as float2 LDS reads.
    float lsum = 0.f;
    {
        const int xp = t & 31;
        const int x  = xp << 1;
        const int yb = (t >> 5) << 1;
        float m1[2][2], m2[2][2], ea[2][2], eb[2][2], ec[2][2];
        #pragma unroll
        for (int p = 0; p < 2; ++p)
            #pragma unroll
            for (int c = 0; c < 2; ++c)
            { m1[p][c]=0.f; m2[p][c]=0.f; ea[p][c]=0.f; eb[p][c]=0.f; ec[p][c]=0.f; }

        #pragma unroll
        for (int k = 0; k < 12; ++k) {
            const int o = (yb + k) * LS + x;
            const float2 vA  = *(const float2*)&h[0][o];
            const float2 vB  = *(const float2*)&h[1][o];
            const float2 vAA = *(const float2*)&h[2][o];
            const float2 vBB = *(const float2*)&h[3][o];
            const float2 vAB = *(const float2*)&h[4][o];
            #pragma unroll
            for (int p = 0; p < 2; ++p) {
                const int kk = k - p;
                if (kk >= 0 && kk <= 10) {
                    const float w = g[kk];
                    m1[p][0] += w * vA.x;  m1[p][1] += w * vA.y;
                    m2[p][0] += w * vB.x;  m2[p][1] += w * vB.y;
                    ea[p][0] += w * vAA.x; ea[p][1] += w * vAA.y;
                    eb[p][0] += w * vBB.x; eb[p][1] += w * vBB.y;
                    ec[p][0] += w * vAB.x; ec[p][1] += w * vAB.y;
                }
            }
        }

        #pragma unroll
        for (int p = 0; p < 2; ++p) {
            #pragma unroll
            for (int c = 0; c < 2; ++c) {
                const float mu1 = m1[p][c], mu2 = m2[p][c];
                const float mu1s = mu1 * mu1, mu2s = mu2 * mu2, mu12 = mu1 * mu2;
                const float s1  = ea[p][c] - mu1s;
                const float s2  = eb[p][c] - mu2s;
                const float s12 = ec[p][c] - mu12;
                const float num = (2.f * mu12 + C1F) * (2.f * s12 + C2F);
                const float den = (mu1s + mu2s + C1F) * (s1 + s2 + C2F);
                float rd = __builtin_amdgcn_rcpf(den);
                rd = rd * (2.f - den * rd);       // one NR step -> ~full f32
                lsum += num * rd;
            }
        }
    }

    // ---------------- reduction ----------------
    #pragma unroll
    for (int off = 32; off > 0; off >>= 1)
        lsum += __shfl_down(lsum, off, 64);

    __syncthreads();                  // all LDS reads done; reuse h[0] for partials
    if ((t & 63) == 0) h[0][t >> 6] = lsum;
    __syncthreads();
    if (t == 0) {
        const double bs = (double)h[0][0] + (double)h[0][1]
                        + (double)h[0][2] + (double)h[0][3];
        atomicAdd(acc, bs);
    }
}

extern "C" void kernel_launch(void* const* d_in, const int* in_sizes, int n_in,
                              void* d_out, int out_size, void* d_ws, size_t ws_size,
                              hipStream_t stream) {
    const float* A = (const float*)d_in[0];
    const float* B = (const float*)d_in[1];
    float* out  = (float*)d_out;
    double* acc = (double*)d_ws;

    ssim_zero<<<dim3(1), dim3(1), 0, stream>>>(acc);
    dim3 grid(IMG / TX, IMG / TY, 48);   // (8, 32, 48) = 12288 blocks
    ssim_main<<<grid, dim3(256), 0, stream>>>(A, B, acc);
    ssim_finalize<<<dim3(1), dim3(1), 0, stream>>>(acc, out);
}

// Round 4
// 173.935 us; speedup vs baseline: 1.4275x; 1.4275x over previous
//
#include <hip/hip_runtime.h>
#include <math.h>

// SSIM fused kernel for MI355X (gfx950), v4.
// A,B: [16,3,512,512] f32 -> scalar f32 mean(ssim_map).
// Separable 11-tap Gaussian, zero-padded SAME conv.
// v4 = v3 with the plane-4 stride bug fixed:
//  - interleaved LDS layout hbuf[42][324]: per-row plane offsets
//    {0,65,130,195,260}, plane 4 width 64 (no row aliasing).
//    54,432B -> rounds to 54,528 -> 3 blocks/CU.
//  - 64 spread f64 accumulator slots (kills the same-line atomic serializer
//    measured in v1/v2: ~15ns per same-address f64 RMW gated block retire).

#define IMG 512
#define C1F 1.0e-4f
#define C2F 9.0e-4f

#define SR 42                // h-rows per tile (TY=32 + 10 halo)
#define RS 324               // LDS row stride in floats (=4 mod 32: bank spread)
// per-row plane offsets: 0, 65, 130, 195, 260 (plane 4 width 64: 260+63=323<324)

__global__ void ssim_zero(double* acc) {
    if (threadIdx.x < 64) acc[(size_t)threadIdx.x * 8] = 0.0;
}

__global__ void ssim_finalize(const double* __restrict__ acc, float* __restrict__ out) {
    double v = acc[(size_t)threadIdx.x * 8];   // 64 threads, 1 wave
    #pragma unroll
    for (int off = 32; off > 0; off >>= 1)
        v += __shfl_down(v, off, 64);
    if (threadIdx.x == 0) *out = (float)(v / 12582912.0);  // 16*3*512*512
}

__device__ __forceinline__ void make_weights(float* g) {
    // Bit-identical to: g[i]=expf(-(i-5)^2/4.5f); gs=sum(i=0..10); g[i]/=gs
    float e[6];
    #pragma unroll
    for (int k = 0; k < 6; ++k) {
        const float d = (float)k;               // |i-5|
        e[k] = expf(-d * d / 4.5f);
    }
    // reference accumulation order i=0..10 -> e5,e4,e3,e2,e1,e0,e1,...,e5
    float gs = e[5];
    gs += e[4]; gs += e[3]; gs += e[2]; gs += e[1]; gs += e[0];
    gs += e[1]; gs += e[2]; gs += e[3]; gs += e[4]; gs += e[5];
    float q[6];
    #pragma unroll
    for (int k = 0; k < 6; ++k) q[k] = e[k] / gs;  // same f32 div as reference
    #pragma unroll
    for (int i = 0; i < 11; ++i) {
        const int d = (i < 5) ? (5 - i) : (i - 5);
        g[i] = q[d];
    }
}

__global__ __launch_bounds__(256, 3)
void ssim_main(const float* __restrict__ A, const float* __restrict__ B,
               double* __restrict__ acc)
{
    __shared__ float hbuf[SR * RS];   // 13,608 floats = 54,432 B

    const int t  = threadIdx.x;
    const int x0 = blockIdx.x * 64;
    const int y0 = blockIdx.y * 32;
    const size_t pbase = (size_t)blockIdx.z * (size_t)(IMG * IMG);
    const float* __restrict__ pa = A + pbase;
    const float* __restrict__ pb = B + pbase;

    float g[11];
    make_weights(g);

    // ---------------- horizontal pass ----------------
    // 252 threads: r = t/6 (0..41), s = t%6. Segment s covers 11 output cols
    // starting at {0,11,22,33,44,53} (segs 4,5 overlap at cols 53,54: same
    // bit-identical value double-written, benign). Window: [start-5, start+15].
    if (t < 252) {
        const int r = t / 6;
        const int s = t - 6 * r;
        const int start = (s == 5) ? 53 : s * 11;
        const int gy  = y0 - 5 + r;
        const int gx0 = x0 + start - 5;
        const bool rowok = ((unsigned)gy < (unsigned)IMG);
        const float* __restrict__ ra = pa + (ptrdiff_t)gy * IMG;
        const float* __restrict__ rb = pb + (ptrdiff_t)gy * IMG;

        float wa[21], wb[21];
        if (rowok && gx0 >= 0 && gx0 + 20 < IMG) {
            #pragma unroll
            for (int j = 0; j < 21; ++j) {       // imm-offset scalar loads
                wa[j] = ra[gx0 + j];
                wb[j] = rb[gx0 + j];
            }
        } else {
            #pragma unroll
            for (int j = 0; j < 21; ++j) {
                const int gx = gx0 + j;
                const bool ok = rowok && ((unsigned)gx < (unsigned)IMG);
                wa[j] = ok ? ra[gx] : 0.f;
                wb[j] = ok ? rb[gx] : 0.f;
            }
        }

        // products-once scatter: 121 (m,p) pairs x 5 FMA
        float sa[11], sb[11], saa[11], sbb[11], sab[11];
        #pragma unroll
        for (int p = 0; p < 11; ++p)
        { sa[p]=0.f; sb[p]=0.f; saa[p]=0.f; sbb[p]=0.f; sab[p]=0.f; }
        #pragma unroll
        for (int m = 0; m < 21; ++m) {
            const float a = wa[m];
            const float b = wb[m];
            const float aa = a * a, bb = b * b, ab = a * b;
            #pragma unroll
            for (int p = 0; p < 11; ++p) {
                const int k = m - p;             // tap index (compile-time)
                if (k >= 0 && k <= 10) {
                    const float w = g[k];
                    sa[p]  += w * a;  sb[p]  += w * b;
                    saa[p] += w * aa; sbb[p] += w * bb; sab[p] += w * ab;
                }
            }
        }

        const int base = r * RS + start;
        #pragma unroll
        for (int p = 0; p < 11; ++p) {
            hbuf[base + p]        = sa[p];
            hbuf[base + 65 + p]   = sb[p];
            hbuf[base + 130 + p]  = saa[p];
            hbuf[base + 195 + p]  = sbb[p];
            hbuf[base + 260 + p]  = sab[p];
        }
    }
    __syncthreads();

    // ---------------- vertical pass + SSIM ----------------
    // 256 threads: column x = t&63, output rows yb..yb+7 (yb = (t>>6)*8).
    float lsum = 0.f;
    {
        const int x  = t & 63;
        const int yb = (t >> 6) << 3;
        float m1[8], m2[8], ea[8], eb[8], ec[8];
        #pragma unroll
        for (int j = 0; j < 8; ++j)
        { m1[j]=0.f; m2[j]=0.f; ea[j]=0.f; eb[j]=0.f; ec[j]=0.f; }

        #pragma unroll
        for (int k = 0; k < 18; ++k) {
            const int o = (yb + k) * RS + x;
            const float vA  = hbuf[o];
            const float vB  = hbuf[o + 65];
            const float vAA = hbuf[o + 130];
            const float vBB = hbuf[o + 195];
            const float vAB = hbuf[o + 260];
            #pragma unroll
            for (int j = 0; j < 8; ++j) {
                const int kk = k - j;
                if (kk >= 0 && kk <= 10) {
                    const float w = g[kk];
                    m1[j] += w * vA;  m2[j] += w * vB;
                    ea[j] += w * vAA; eb[j] += w * vBB; ec[j] += w * vAB;
                }
            }
        }

        #pragma unroll
        for (int j = 0; j < 8; ++j) {
            const float mu1 = m1[j], mu2 = m2[j];
            const float mu1s = mu1 * mu1, mu2s = mu2 * mu2, mu12 = mu1 * mu2;
            const float s1  = ea[j] - mu1s;
            const float s2  = eb[j] - mu2s;
            const float s12 = ec[j] - mu12;
            const float num = (2.f * mu12 + C1F) * (2.f * s12 + C2F);
            const float den = (mu1s + mu2s + C1F) * (s1 + s2 + C2F);
            float rd = __builtin_amdgcn_rcpf(den);
            rd = rd * (2.f - den * rd);          // one NR step
            lsum += num * rd;
        }
    }

    // ---------------- reduction ----------------
    #pragma unroll
    for (int off = 32; off > 0; off >>= 1)
        lsum += __shfl_down(lsum, off, 64);

    __syncthreads();                  // LDS reads done; reuse hbuf for partials
    if ((t & 63) == 0) hbuf[t >> 6] = lsum;
    __syncthreads();
    if (t == 0) {
        const double bs = (double)hbuf[0] + (double)hbuf[1]
                        + (double)hbuf[2] + (double)hbuf[3];
        const int slot = (blockIdx.x + (blockIdx.y << 3) + (blockIdx.z << 8)) & 63;
        atomicAdd(&acc[(size_t)slot * 8], bs);   // 64 spread cachelines
    }
}

extern "C" void kernel_launch(void* const* d_in, const int* in_sizes, int n_in,
                              void* d_out, int out_size, void* d_ws, size_t ws_size,
                              hipStream_t stream) {
    const float* A = (const float*)d_in[0];
    const float* B = (const float*)d_in[1];
    float* out  = (float*)d_out;
    double* acc = (double*)d_ws;                 // 64 slots x 64B = 4KB

    ssim_zero<<<dim3(1), dim3(64), 0, stream>>>(acc);
    dim3 grid(IMG / 64, IMG / 32, 48);           // (8, 16, 48) = 6144 blocks
    ssim_main<<<grid, dim3(256), 0, stream>>>(A, B, acc);
    ssim_finalize<<<dim3(1), dim3(64), 0, stream>>>(acc, out);
}

// Round 5
// 170.030 us; speedup vs baseline: 1.4603x; 1.0230x over previous
//
#include <hip/hip_runtime.h>
#include <math.h>

// SSIM fused kernel for MI355X (gfx950), v5.
// A,B: [16,3,512,512] f32 -> scalar f32 mean(ssim_map).
// Separable 11-tap Gaussian, zero-padded SAME conv.
// v5 = v4 with:
//  - LDS row stride 324 -> 323 (plane offsets {0,65,130,195,259}; planes 3,4
//    exactly 64 wide). Raw 54,264B -> 512B-granular alloc 54,272 -> 3 blk/CU
//    (v4's 54,432 rounded to 54,784, overflowing 160KiB by 512B at x3).
//  - no atomics: per-block partial -> private d_ws slot (6144 doubles),
//    finalize kernel reduces. Removes ssim_zero launch.

#define IMG 512
#define C1F 1.0e-4f
#define C2F 9.0e-4f

#define SR 42                // h-rows per tile (TY=32 + 10 halo)
#define RS 323               // LDS row stride in floats
// per-row plane offsets: 0, 65, 130, 195, 259 (planes 3,4 width exactly 64)

#define NBLK 6144            // 8 * 16 * 48

__global__ void ssim_finalize(const double* __restrict__ part, float* __restrict__ out) {
    const int t = threadIdx.x;           // 256 threads
    double v = 0.0;
    #pragma unroll
    for (int i = 0; i < NBLK / 256; ++i)     // 24 iters
        v += part[t + 256 * i];
    #pragma unroll
    for (int off = 32; off > 0; off >>= 1)
        v += __shfl_down(v, off, 64);
    __shared__ double w[4];
    if ((t & 63) == 0) w[t >> 6] = v;
    __syncthreads();
    if (t == 0)
        *out = (float)((w[0] + w[1] + w[2] + w[3]) / 12582912.0);  // 16*3*512^2
}

__device__ __forceinline__ void make_weights(float* g) {
    // Bit-identical to: g[i]=expf(-(i-5)^2/4.5f); gs=sum(i=0..10); g[i]/=gs
    float e[6];
    #pragma unroll
    for (int k = 0; k < 6; ++k) {
        const float d = (float)k;               // |i-5|
        e[k] = expf(-d * d / 4.5f);
    }
    // reference accumulation order i=0..10 -> e5,e4,e3,e2,e1,e0,e1,...,e5
    float gs = e[5];
    gs += e[4]; gs += e[3]; gs += e[2]; gs += e[1]; gs += e[0];
    gs += e[1]; gs += e[2]; gs += e[3]; gs += e[4]; gs += e[5];
    float q[6];
    #pragma unroll
    for (int k = 0; k < 6; ++k) q[k] = e[k] / gs;  // same f32 div as reference
    #pragma unroll
    for (int i = 0; i < 11; ++i) {
        const int d = (i < 5) ? (5 - i) : (i - 5);
        g[i] = q[d];
    }
}

__global__ __launch_bounds__(256, 3)
void ssim_main(const float* __restrict__ A, const float* __restrict__ B,
               double* __restrict__ part)
{
    __shared__ float hbuf[SR * RS];   // 13,566 floats = 54,264 B

    const int t  = threadIdx.x;
    const int x0 = blockIdx.x * 64;
    const int y0 = blockIdx.y * 32;
    const size_t pbase = (size_t)blockIdx.z * (size_t)(IMG * IMG);
    const float* __restrict__ pa = A + pbase;
    const float* __restrict__ pb = B + pbase;

    float g[11];
    make_weights(g);

    // ---------------- horizontal pass ----------------
    // 252 threads: r = t/6 (0..41), s = t%6. Segment s covers 11 output cols
    // starting at {0,11,22,33,44,53} (segs 4,5 overlap at cols 53,54: same
    // bit-identical value double-written, benign). Window: [start-5, start+15].
    if (t < 252) {
        const int r = t / 6;
        const int s = t - 6 * r;
        const int start = (s == 5) ? 53 : s * 11;
        const int gy  = y0 - 5 + r;
        const int gx0 = x0 + start - 5;
        const bool rowok = ((unsigned)gy < (unsigned)IMG);
        const float* __restrict__ ra = pa + (ptrdiff_t)gy * IMG;
        const float* __restrict__ rb = pb + (ptrdiff_t)gy * IMG;

        float wa[21], wb[21];
        if (rowok && gx0 >= 0 && gx0 + 20 < IMG) {
            #pragma unroll
            for (int j = 0; j < 21; ++j) {       // imm-offset scalar loads
                wa[j] = ra[gx0 + j];
                wb[j] = rb[gx0 + j];
            }
        } else {
            #pragma unroll
            for (int j = 0; j < 21; ++j) {
                const int gx = gx0 + j;
                const bool ok = rowok && ((unsigned)gx < (unsigned)IMG);
                wa[j] = ok ? ra[gx] : 0.f;
                wb[j] = ok ? rb[gx] : 0.f;
            }
        }

        // products-once scatter: 121 (m,p) pairs x 5 FMA
        float sa[11], sb[11], saa[11], sbb[11], sab[11];
        #pragma unroll
        for (int p = 0; p < 11; ++p)
        { sa[p]=0.f; sb[p]=0.f; saa[p]=0.f; sbb[p]=0.f; sab[p]=0.f; }
        #pragma unroll
        for (int m = 0; m < 21; ++m) {
            const float a = wa[m];
            const float b = wb[m];
            const float aa = a * a, bb = b * b, ab = a * b;
            #pragma unroll
            for (int p = 0; p < 11; ++p) {
                const int k = m - p;             // tap index (compile-time)
                if (k >= 0 && k <= 10) {
                    const float w = g[k];
                    sa[p]  += w * a;  sb[p]  += w * b;
                    saa[p] += w * aa; sbb[p] += w * bb; sab[p] += w * ab;
                }
            }
        }

        const int base = r * RS + start;
        #pragma unroll
        for (int p = 0; p < 11; ++p) {
            hbuf[base + p]        = sa[p];
            hbuf[base + 65 + p]   = sb[p];
            hbuf[base + 130 + p]  = saa[p];
            hbuf[base + 195 + p]  = sbb[p];
            hbuf[base + 259 + p]  = sab[p];
        }
    }
    __syncthreads();

    // ---------------- vertical pass + SSIM ----------------
    // 256 threads: column x = t&63, output rows yb..yb+7 (yb = (t>>6)*8).
    float lsum = 0.f;
    {
        const int x  = t & 63;
        const int yb = (t >> 6) << 3;
        float m1[8], m2[8], ea[8], eb[8], ec[8];
        #pragma unroll
        for (int j = 0; j < 8; ++j)
        { m1[j]=0.f; m2[j]=0.f; ea[j]=0.f; eb[j]=0.f; ec[j]=0.f; }

        #pragma unroll
        for (int k = 0; k < 18; ++k) {
            const int o = (yb + k) * RS + x;
            const float vA  = hbuf[o];
            const float vB  = hbuf[o + 65];
            const float vAA = hbuf[o + 130];
            const float vBB = hbuf[o + 195];
            const float vAB = hbuf[o + 259];
            #pragma unroll
            for (int j = 0; j < 8; ++j) {
                const int kk = k - j;
                if (kk >= 0 && kk <= 10) {
                    const float w = g[kk];
                    m1[j] += w * vA;  m2[j] += w * vB;
                    ea[j] += w * vAA; eb[j] += w * vBB; ec[j] += w * vAB;
                }
            }
        }

        #pragma unroll
        for (int j = 0; j < 8; ++j) {
            const float mu1 = m1[j], mu2 = m2[j];
            const float mu1s = mu1 * mu1, mu2s = mu2 * mu2, mu12 = mu1 * mu2;
            const float s1  = ea[j] - mu1s;
            const float s2  = eb[j] - mu2s;
            const float s12 = ec[j] - mu12;
            const float num = (2.f * mu12 + C1F) * (2.f * s12 + C2F);
            const float den = (mu1s + mu2s + C1F) * (s1 + s2 + C2F);
            float rd = __builtin_amdgcn_rcpf(den);
            rd = rd * (2.f - den * rd);          // one NR step
            lsum += num * rd;
        }
    }

    // ---------------- reduction ----------------
    #pragma unroll
    for (int off = 32; off > 0; off >>= 1)
        lsum += __shfl_down(lsum, off, 64);

    __syncthreads();                  // LDS reads done; reuse hbuf for partials
    if ((t & 63) == 0) hbuf[t >> 6] = lsum;
    __syncthreads();
    if (t == 0) {
        const double bs = (double)hbuf[0] + (double)hbuf[1]
                        + (double)hbuf[2] + (double)hbuf[3];
        const int slot = blockIdx.x + (blockIdx.y << 3) + (blockIdx.z << 7);
        part[slot] = bs;              // private slot, no atomics
    }
}

extern "C" void kernel_launch(void* const* d_in, const int* in_sizes, int n_in,
                              void* d_out, int out_size, void* d_ws, size_t ws_size,
                              hipStream_t stream) {
    const float* A = (const float*)d_in[0];
    const float* B = (const float*)d_in[1];
    float* out   = (float*)d_out;
    double* part = (double*)d_ws;                // 6144 doubles = 48KB

    dim3 grid(IMG / 64, IMG / 32, 48);           // (8, 16, 48) = 6144 blocks
    ssim_main<<<grid, dim3(256), 0, stream>>>(A, B, part);
    ssim_finalize<<<dim3(1), dim3(256), 0, stream>>>(part, out);
}

// Round 6
// 158.801 us; speedup vs baseline: 1.5636x; 1.0707x over previous
//
#include <hip/hip_runtime.h>
#include <math.h>

// SSIM fused kernel for MI355X (gfx950), v6.
// A,B: [16,3,512,512] f32 -> scalar f32 mean(ssim_map).
// Separable 11-tap Gaussian, zero-padded SAME conv.
// v6 = v5 with the 5 LDS planes reduced to 4 via linearity:
//   sigma1_sq + sigma2_sq = conv(A^2 + B^2) - mu1^2 - mu2^2
// so we stage {hA, hB, h(A^2+B^2), h(AB)}. -20% conv FMAs, -20% LDS traffic,
// LDS 43,520B -> 3 blocks/CU with 33KB margin (v5's 54,272 x3 left only 1KB
// and the 3rd block never materialized: occupancy stayed 19%).

#define IMG 512
#define C1F 1.0e-4f
#define C2F 9.0e-4f

#define SR 42                // h-rows per tile (TY=32 + 10 halo)
#define RS 259               // LDS row stride in floats (=3 mod 32)
// per-row plane offsets: 0, 65, 130, 195 (plane 3 width exactly 64: 195+63=258)

#define NBLK 6144            // 8 * 16 * 48

__global__ void ssim_finalize(const double* __restrict__ part, float* __restrict__ out) {
    const int t = threadIdx.x;           // 256 threads
    double v = 0.0;
    #pragma unroll
    for (int i = 0; i < NBLK / 256; ++i)     // 24 iters
        v += part[t + 256 * i];
    #pragma unroll
    for (int off = 32; off > 0; off >>= 1)
        v += __shfl_down(v, off, 64);
    __shared__ double w[4];
    if ((t & 63) == 0) w[t >> 6] = v;
    __syncthreads();
    if (t == 0)
        *out = (float)((w[0] + w[1] + w[2] + w[3]) / 12582912.0);  // 16*3*512^2
}

__device__ __forceinline__ void make_weights(float* g) {
    // Bit-identical to: g[i]=expf(-(i-5)^2/4.5f); gs=sum(i=0..10); g[i]/=gs
    float e[6];
    #pragma unroll
    for (int k = 0; k < 6; ++k) {
        const float d = (float)k;               // |i-5|
        e[k] = expf(-d * d / 4.5f);
    }
    // reference accumulation order i=0..10 -> e5,e4,e3,e2,e1,e0,e1,...,e5
    float gs = e[5];
    gs += e[4]; gs += e[3]; gs += e[2]; gs += e[1]; gs += e[0];
    gs += e[1]; gs += e[2]; gs += e[3]; gs += e[4]; gs += e[5];
    float q[6];
    #pragma unroll
    for (int k = 0; k < 6; ++k) q[k] = e[k] / gs;  // same f32 div as reference
    #pragma unroll
    for (int i = 0; i < 11; ++i) {
        const int d = (i < 5) ? (5 - i) : (i - 5);
        g[i] = q[d];
    }
}

__global__ __launch_bounds__(256, 3)
void ssim_main(const float* __restrict__ A, const float* __restrict__ B,
               double* __restrict__ part)
{
    __shared__ float hbuf[SR * RS];   // 10,878 floats = 43,512 B

    const int t  = threadIdx.x;
    const int x0 = blockIdx.x * 64;
    const int y0 = blockIdx.y * 32;
    const size_t pbase = (size_t)blockIdx.z * (size_t)(IMG * IMG);
    const float* __restrict__ pa = A + pbase;
    const float* __restrict__ pb = B + pbase;

    float g[11];
    make_weights(g);

    // ---------------- horizontal pass ----------------
    // 252 threads: r = t/6 (0..41), s = t%6. Segment s covers 11 output cols
    // starting at {0,11,22,33,44,53} (segs 4,5 overlap at cols 53,54: same
    // bit-identical value double-written, benign). Window: [start-5, start+15].
    if (t < 252) {
        const int r = t / 6;
        const int s = t - 6 * r;
        const int start = (s == 5) ? 53 : s * 11;
        const int gy  = y0 - 5 + r;
        const int gx0 = x0 + start - 5;
        const bool rowok = ((unsigned)gy < (unsigned)IMG);
        const float* __restrict__ ra = pa + (ptrdiff_t)gy * IMG;
        const float* __restrict__ rb = pb + (ptrdiff_t)gy * IMG;

        float wa[21], wb[21];
        if (rowok && gx0 >= 0 && gx0 + 20 < IMG) {
            #pragma unroll
            for (int j = 0; j < 21; ++j) {       // imm-offset scalar loads
                wa[j] = ra[gx0 + j];
                wb[j] = rb[gx0 + j];
            }
        } else {
            #pragma unroll
            for (int j = 0; j < 21; ++j) {
                const int gx = gx0 + j;
                const bool ok = rowok && ((unsigned)gx < (unsigned)IMG);
                wa[j] = ok ? ra[gx] : 0.f;
                wb[j] = ok ? rb[gx] : 0.f;
            }
        }

        // products-once scatter: 121 (m,p) pairs x 4 FMA
        float sa[11], sb[11], ss[11], sp[11];
        #pragma unroll
        for (int p = 0; p < 11; ++p)
        { sa[p]=0.f; sb[p]=0.f; ss[p]=0.f; sp[p]=0.f; }
        #pragma unroll
        for (int m = 0; m < 21; ++m) {
            const float a = wa[m];
            const float b = wb[m];
            const float s2v = a * a + b * b;     // A^2 + B^2 (conv is linear)
            const float ab  = a * b;
            #pragma unroll
            for (int p = 0; p < 11; ++p) {
                const int k = m - p;             // tap index (compile-time)
                if (k >= 0 && k <= 10) {
                    const float w = g[k];
                    sa[p] += w * a;   sb[p] += w * b;
                    ss[p] += w * s2v; sp[p] += w * ab;
                }
            }
        }

        const int base = r * RS + start;
        #pragma unroll
        for (int p = 0; p < 11; ++p) {
            hbuf[base + p]        = sa[p];
            hbuf[base + 65 + p]   = sb[p];
            hbuf[base + 130 + p]  = ss[p];
            hbuf[base + 195 + p]  = sp[p];
        }
    }
    __syncthreads();

    // ---------------- vertical pass + SSIM ----------------
    // 256 threads: column x = t&63, output rows yb..yb+7 (yb = (t>>6)*8).
    float lsum = 0.f;
    {
        const int x  = t & 63;
        const int yb = (t >> 6) << 3;
        float m1[8], m2[8], es[8], ep[8];
        #pragma unroll
        for (int j = 0; j < 8; ++j)
        { m1[j]=0.f; m2[j]=0.f; es[j]=0.f; ep[j]=0.f; }

        #pragma unroll
        for (int k = 0; k < 18; ++k) {
            const int o = (yb + k) * RS + x;
            const float vA = hbuf[o];
            const float vB = hbuf[o + 65];
            const float vS = hbuf[o + 130];
            const float vP = hbuf[o + 195];
            #pragma unroll
            for (int j = 0; j < 8; ++j) {
                const int kk = k - j;
                if (kk >= 0 && kk <= 10) {
                    const float w = g[kk];
                    m1[j] += w * vA; m2[j] += w * vB;
                    es[j] += w * vS; ep[j] += w * vP;
                }
            }
        }

        #pragma unroll
        for (int j = 0; j < 8; ++j) {
            const float mu1 = m1[j], mu2 = m2[j];
            const float mu1s = mu1 * mu1, mu2s = mu2 * mu2, mu12 = mu1 * mu2;
            const float s12  = ep[j] - mu12;                 // sigma12
            const float ssum = es[j] - mu1s - mu2s;          // sigma1+sigma2
            const float num = (2.f * mu12 + C1F) * (2.f * s12 + C2F);
            const float den = (mu1s + mu2s + C1F) * (ssum + C2F);
            float rd = __builtin_amdgcn_rcpf(den);
            rd = rd * (2.f - den * rd);          // one NR step
            lsum += num * rd;
        }
    }

    // ---------------- reduction ----------------
    #pragma unroll
    for (int off = 32; off > 0; off >>= 1)
        lsum += __shfl_down(lsum, off, 64);

    __syncthreads();                  // LDS reads done; reuse hbuf for partials
    if ((t & 63) == 0) hbuf[t >> 6] = lsum;
    __syncthreads();
    if (t == 0) {
        const double bs = (double)hbuf[0] + (double)hbuf[1]
                        + (double)hbuf[2] + (double)hbuf[3];
        const int slot = blockIdx.x + (blockIdx.y << 3) + (blockIdx.z << 7);
        part[slot] = bs;              // private slot, no atomics
    }
}

extern "C" void kernel_launch(void* const* d_in, const int* in_sizes, int n_in,
                              void* d_out, int out_size, void* d_ws, size_t ws_size,
                              hipStream_t stream) {
    const float* A = (const float*)d_in[0];
    const float* B = (const float*)d_in[1];
    float* out   = (float*)d_out;
    double* part = (double*)d_ws;                // 6144 doubles = 48KB

    dim3 grid(IMG / 64, IMG / 32, 48);           // (8, 16, 48) = 6144 blocks
    ssim_main<<<grid, dim3(256), 0, stream>>>(A, B, part);
    ssim_finalize<<<dim3(1), dim3(256), 0, stream>>>(part, out);
}